// Round 1
// baseline (360.738 us; speedup 1.0000x reference)
//
#include <hip/hip_runtime.h>

typedef __bf16 bf16x8 __attribute__((ext_vector_type(8)));
typedef float f32x4 __attribute__((ext_vector_type(4)));

#define MFMA16 __builtin_amdgcn_mfma_f32_16x16x32_bf16

__device__ __forceinline__ unsigned short f2bf(float f) {
  union { float f; unsigned u; } v; v.f = f;
  unsigned r = v.u + 0x7fffu + ((v.u >> 16) & 1u);
  return (unsigned short)(r >> 16);
}

// ---------------------------------------------------------------------------
// Kernel 1: C[n, 0:3072] = x @ [Wq | Wk | Wv], fused RoPE on Q/K columns.
// Writes Q -> [32][2048][64] bf16, K -> [8][2048][64] bf16, V -> transposed
// [8][64][2048] bf16 (so attention PV B-fragments are contiguous).
// ---------------------------------------------------------------------------
__global__ __launch_bounds__(256)
void qkv_rope_kernel(const float* __restrict__ x, const float* __restrict__ Wq,
                     const float* __restrict__ Wk, const float* __restrict__ Wv,
                     const float* __restrict__ cosT, const float* __restrict__ sinT,
                     unsigned short* __restrict__ Qb, unsigned short* __restrict__ Kb,
                     unsigned short* __restrict__ Vt)
{
  __shared__ unsigned short Alds[128][72];  // [row][k], +8 pad kills bank conflicts
  __shared__ unsigned short Blds[128][72];  // [col][k] (transposed weight tile)
  const int t = threadIdx.x;
  const int w = t >> 6, l = t & 63, g = l >> 4, c = l & 15;
  const int wr = w >> 1, wc = w & 1;
  const int r0 = blockIdx.y * 128;
  const int c0 = blockIdx.x * 128;

  const float* W; int ldb, bcol0;
  if (c0 < 2048)      { W = Wq; ldb = 2048; bcol0 = c0; }
  else if (c0 < 2560) { W = Wk; ldb = 512;  bcol0 = c0 - 2048; }
  else                { W = Wv; ldb = 512;  bcol0 = c0 - 2560; }

  f32x4 acc[4][4];
#pragma unroll
  for (int m = 0; m < 4; ++m)
#pragma unroll
    for (int n = 0; n < 4; ++n) acc[m][n] = (f32x4){0.f, 0.f, 0.f, 0.f};

  for (int kt = 0; kt < 2048; kt += 64) {
    float4 av[8], bv[8];
#pragma unroll
    for (int i = 0; i < 8; ++i) {
      int idx = t + i * 256;
      int row = idx >> 4, k4 = idx & 15;
      av[i] = *(const float4*)&x[(r0 + row) * 2048 + kt + k4 * 4];
    }
#pragma unroll
    for (int i = 0; i < 8; ++i) {
      int idx = t + i * 256;
      int kr = idx >> 5, c4 = idx & 31;
      bv[i] = *(const float4*)&W[(kt + kr) * ldb + bcol0 + c4 * 4];
    }
    __syncthreads();
#pragma unroll
    for (int i = 0; i < 8; ++i) {
      int idx = t + i * 256;
      int row = idx >> 4, k4 = idx & 15;
      ushort4 u;
      u.x = f2bf(av[i].x); u.y = f2bf(av[i].y);
      u.z = f2bf(av[i].z); u.w = f2bf(av[i].w);
      *(ushort4*)&Alds[row][k4 * 4] = u;
    }
#pragma unroll
    for (int i = 0; i < 8; ++i) {
      int idx = t + i * 256;
      int kr = idx >> 5, c4 = idx & 31;
      Blds[c4 * 4 + 0][kr] = f2bf(bv[i].x);
      Blds[c4 * 4 + 1][kr] = f2bf(bv[i].y);
      Blds[c4 * 4 + 2][kr] = f2bf(bv[i].z);
      Blds[c4 * 4 + 3][kr] = f2bf(bv[i].w);
    }
    __syncthreads();
#pragma unroll
    for (int ks = 0; ks < 2; ++ks) {
      bf16x8 aF[4], bF[4];
#pragma unroll
      for (int m = 0; m < 4; ++m)
        aF[m] = *(const bf16x8*)&Alds[wr * 64 + m * 16 + c][ks * 32 + g * 8];
#pragma unroll
      for (int n = 0; n < 4; ++n)
        bF[n] = *(const bf16x8*)&Blds[wc * 64 + n * 16 + c][ks * 32 + g * 8];
#pragma unroll
      for (int m = 0; m < 4; ++m)
#pragma unroll
        for (int n = 0; n < 4; ++n)
          acc[m][n] = MFMA16(aF[m], bF[n], acc[m][n], 0, 0, 0);
    }
  }

  const int wcol0 = c0 + wc * 64;  // wave's 64-col span == exactly one head
  if (c0 < 2560) {
    unsigned short* dst; int hh;
    if (c0 < 2048) { dst = Qb; hh = wcol0 >> 6; }
    else           { dst = Kb; hh = (wcol0 - 2048) >> 6; }
#pragma unroll
    for (int m = 0; m < 4; ++m) {
#pragma unroll
      for (int j = 0; j < 4; ++j) {
        int p = r0 + wr * 64 + m * 16 + g * 4 + j;
#pragma unroll
        for (int n = 0; n < 2; ++n) {  // RoPE pairs: frag n (d<32) with frag n+2 (d+32)
          int d = n * 16 + c;
          float cv = cosT[p * 64 + d];
          float sv = sinT[p * 64 + d];
          float lo = acc[m][n][j], hi = acc[m][n + 2][j];
          dst[(hh * 2048 + p) * 64 + d]      = f2bf(lo * cv - hi * sv);
          dst[(hh * 2048 + p) * 64 + d + 32] = f2bf(hi * cv + lo * sv);
        }
      }
    }
  } else {
    int kvh = (wcol0 - 2560) >> 6;
#pragma unroll
    for (int m = 0; m < 4; ++m) {
      int p0 = r0 + wr * 64 + m * 16 + g * 4;
#pragma unroll
      for (int n = 0; n < 4; ++n) {
        int d = n * 16 + c;
        ushort4 u;
        u.x = f2bf(acc[m][n][0]); u.y = f2bf(acc[m][n][1]);
        u.z = f2bf(acc[m][n][2]); u.w = f2bf(acc[m][n][3]);
        *(ushort4*)&Vt[(kvh * 64 + d) * 2048 + p0] = u;  // transposed store
      }
    }
  }
}

// ---------------------------------------------------------------------------
// Kernel 2: causal GQA flash attention. Block = (head, 128 q-rows); 4
// independent waves x 32 q-rows; KV tile = 64. K/Vt read straight from global
// (L2-resident); P reshaped via wave-private LDS (no barriers).
// ---------------------------------------------------------------------------
__global__ __launch_bounds__(256)
void attn_kernel(const unsigned short* __restrict__ Qb,
                 const unsigned short* __restrict__ Kb,
                 const unsigned short* __restrict__ Vt,
                 unsigned short* __restrict__ ctxO)
{
  __shared__ unsigned short Plds[4][32][72];
  const int t = threadIdx.x, w = t >> 6, l = t & 63, g = l >> 4, c = l & 15;
  const int h = blockIdx.x;
  const int qt = 15 - blockIdx.y;  // heavy (large-q) tiles first
  const int kvh = h >> 2;
  const int qb = qt * 128 + w * 32;

  bf16x8 qf[2][2];
#pragma unroll
  for (int m = 0; m < 2; ++m)
#pragma unroll
    for (int ks = 0; ks < 2; ++ks)
      qf[m][ks] = *(const bf16x8*)&Qb[(h * 2048 + qb + m * 16 + c) * 64 + ks * 32 + g * 8];

  f32x4 ctx[2][4];
  float mrow[2][4], lrow[2][4];
#pragma unroll
  for (int m = 0; m < 2; ++m) {
#pragma unroll
    for (int n = 0; n < 4; ++n) ctx[m][n] = (f32x4){0.f, 0.f, 0.f, 0.f};
#pragma unroll
    for (int j = 0; j < 4; ++j) { mrow[m][j] = -1e30f; lrow[m][j] = 0.f; }
  }

  const int ntile = (qb + 32 + 63) >> 6;
  for (int ti = 0; ti < ntile; ++ti) {
    const int kvb = ti * 64;
    f32x4 S[2][4];
#pragma unroll
    for (int m = 0; m < 2; ++m)
#pragma unroll
      for (int n = 0; n < 4; ++n) S[m][n] = (f32x4){0.f, 0.f, 0.f, 0.f};

#pragma unroll
    for (int ks = 0; ks < 2; ++ks) {
      bf16x8 kF[4];
#pragma unroll
      for (int nn = 0; nn < 4; ++nn)
        kF[nn] = *(const bf16x8*)&Kb[(kvh * 2048 + kvb + nn * 16 + c) * 64 + ks * 32 + g * 8];
#pragma unroll
      for (int m = 0; m < 2; ++m)
#pragma unroll
        for (int nn = 0; nn < 4; ++nn)
          S[m][nn] = MFMA16(qf[m][ks], kF[nn], S[m][nn], 0, 0, 0);
    }

    const bool diag = (kvb + 63 > qb);
#pragma unroll
    for (int m = 0; m < 2; ++m)
#pragma unroll
      for (int nn = 0; nn < 4; ++nn)
#pragma unroll
        for (int j = 0; j < 4; ++j) {
          float v = S[m][nn][j] * 0.125f;
          if (diag) {
            int qpos = qb + m * 16 + g * 4 + j;
            int kpos = kvb + nn * 16 + c;
            if (kpos > qpos) v = -1e30f;
          }
          S[m][nn][j] = v;
        }

    float fac[2][4];
#pragma unroll
    for (int m = 0; m < 2; ++m)
#pragma unroll
      for (int j = 0; j < 4; ++j) {
        float tm = fmaxf(fmaxf(S[m][0][j], S[m][1][j]), fmaxf(S[m][2][j], S[m][3][j]));
        tm = fmaxf(tm, __shfl_xor(tm, 1));
        tm = fmaxf(tm, __shfl_xor(tm, 2));
        tm = fmaxf(tm, __shfl_xor(tm, 4));
        tm = fmaxf(tm, __shfl_xor(tm, 8));
        float mn = fmaxf(mrow[m][j], tm);
        fac[m][j] = __expf(mrow[m][j] - mn);
        mrow[m][j] = mn;
      }

#pragma unroll
    for (int m = 0; m < 2; ++m)
#pragma unroll
      for (int j = 0; j < 4; ++j) {
        float rs = 0.f;
#pragma unroll
        for (int nn = 0; nn < 4; ++nn) {
          float p = __expf(S[m][nn][j] - mrow[m][j]);
          S[m][nn][j] = p;
          rs += p;
        }
        rs += __shfl_xor(rs, 1);
        rs += __shfl_xor(rs, 2);
        rs += __shfl_xor(rs, 4);
        rs += __shfl_xor(rs, 8);
        lrow[m][j] = lrow[m][j] * fac[m][j] + rs;
      }

#pragma unroll
    for (int m = 0; m < 2; ++m)
#pragma unroll
      for (int n = 0; n < 4; ++n)
#pragma unroll
        for (int j = 0; j < 4; ++j) ctx[m][n][j] *= fac[m][j];

    // P: C-layout -> A-layout via wave-private LDS round trip
#pragma unroll
    for (int m = 0; m < 2; ++m)
#pragma unroll
      for (int nn = 0; nn < 4; ++nn)
#pragma unroll
        for (int j = 0; j < 4; ++j)
          Plds[w][m * 16 + g * 4 + j][nn * 16 + c] = f2bf(S[m][nn][j]);

    bf16x8 pf[2][2];
#pragma unroll
    for (int m = 0; m < 2; ++m)
#pragma unroll
      for (int ks = 0; ks < 2; ++ks)
        pf[m][ks] = *(const bf16x8*)&Plds[w][m * 16 + c][ks * 32 + g * 8];

#pragma unroll
    for (int ks = 0; ks < 2; ++ks) {
      bf16x8 vF[4];
#pragma unroll
      for (int n = 0; n < 4; ++n)
        vF[n] = *(const bf16x8*)&Vt[(kvh * 64 + n * 16 + c) * 2048 + kvb + ks * 32 + g * 8];
#pragma unroll
      for (int m = 0; m < 2; ++m)
#pragma unroll
        for (int n = 0; n < 4; ++n)
          ctx[m][n] = MFMA16(pf[m][ks], vF[n], ctx[m][n], 0, 0, 0);
    }
  }

  float inv[2][4];
#pragma unroll
  for (int m = 0; m < 2; ++m)
#pragma unroll
    for (int j = 0; j < 4; ++j) inv[m][j] = 1.f / lrow[m][j];
#pragma unroll
  for (int m = 0; m < 2; ++m)
#pragma unroll
    for (int n = 0; n < 4; ++n)
#pragma unroll
      for (int j = 0; j < 4; ++j) {
        int p = qb + m * 16 + g * 4 + j;
        int d = n * 16 + c;
        ctxO[p * 2048 + h * 64 + d] = f2bf(ctx[m][n][j] * inv[m][j]);
      }
}

// ---------------------------------------------------------------------------
// Kernel 3: out = ctx(bf16) @ Wo(fp32 -> bf16 staged), fp32 output.
// ---------------------------------------------------------------------------
__global__ __launch_bounds__(256)
void out_gemm_kernel(const unsigned short* __restrict__ ctxB,
                     const float* __restrict__ Wo, float* __restrict__ out)
{
  __shared__ unsigned short Alds[128][72];
  __shared__ unsigned short Blds[128][72];
  const int t = threadIdx.x;
  const int w = t >> 6, l = t & 63, g = l >> 4, c = l & 15;
  const int wr = w >> 1, wc = w & 1;
  const int r0 = blockIdx.y * 128;
  const int c0 = blockIdx.x * 128;

  f32x4 acc[4][4];
#pragma unroll
  for (int m = 0; m < 4; ++m)
#pragma unroll
    for (int n = 0; n < 4; ++n) acc[m][n] = (f32x4){0.f, 0.f, 0.f, 0.f};

  for (int kt = 0; kt < 2048; kt += 64) {
    uint4 av[4];
    float4 bv[8];
#pragma unroll
    for (int i = 0; i < 4; ++i) {
      int idx = t + i * 256;
      int row = idx >> 3, k8 = idx & 7;
      av[i] = *(const uint4*)&ctxB[(r0 + row) * 2048 + kt + k8 * 8];
    }
#pragma unroll
    for (int i = 0; i < 8; ++i) {
      int idx = t + i * 256;
      int kr = idx >> 5, c4 = idx & 31;
      bv[i] = *(const float4*)&Wo[(kt + kr) * 2048 + c0 + c4 * 4];
    }
    __syncthreads();
#pragma unroll
    for (int i = 0; i < 4; ++i) {
      int idx = t + i * 256;
      int row = idx >> 3, k8 = idx & 7;
      *(uint4*)&Alds[row][k8 * 8] = av[i];
    }
#pragma unroll
    for (int i = 0; i < 8; ++i) {
      int idx = t + i * 256;
      int kr = idx >> 5, c4 = idx & 31;
      Blds[c4 * 4 + 0][kr] = f2bf(bv[i].x);
      Blds[c4 * 4 + 1][kr] = f2bf(bv[i].y);
      Blds[c4 * 4 + 2][kr] = f2bf(bv[i].z);
      Blds[c4 * 4 + 3][kr] = f2bf(bv[i].w);
    }
    __syncthreads();
#pragma unroll
    for (int ks = 0; ks < 2; ++ks) {
      bf16x8 aF[4], bF[4];
#pragma unroll
      for (int m = 0; m < 4; ++m)
        aF[m] = *(const bf16x8*)&Alds[wr * 64 + m * 16 + c][ks * 32 + g * 8];
#pragma unroll
      for (int n = 0; n < 4; ++n)
        bF[n] = *(const bf16x8*)&Blds[wc * 64 + n * 16 + c][ks * 32 + g * 8];
#pragma unroll
      for (int m = 0; m < 4; ++m)
#pragma unroll
        for (int n = 0; n < 4; ++n)
          acc[m][n] = MFMA16(aF[m], bF[n], acc[m][n], 0, 0, 0);
    }
  }

#pragma unroll
  for (int m = 0; m < 4; ++m)
#pragma unroll
    for (int j = 0; j < 4; ++j) {
      int p = r0 + wr * 64 + m * 16 + g * 4 + j;
#pragma unroll
      for (int n = 0; n < 4; ++n)
        out[p * 2048 + c0 + wc * 64 + n * 16 + c] = acc[m][n][j];
    }
}

// ---------------------------------------------------------------------------
extern "C" void kernel_launch(void* const* d_in, const int* in_sizes, int n_in,
                              void* d_out, int out_size, void* d_ws, size_t ws_size,
                              hipStream_t stream) {
  const float* x    = (const float*)d_in[0];
  const float* Wq   = (const float*)d_in[1];
  const float* Wk   = (const float*)d_in[2];
  const float* Wv   = (const float*)d_in[3];
  const float* Wo   = (const float*)d_in[4];
  const float* cosT = (const float*)d_in[5];
  const float* sinT = (const float*)d_in[6];
  float* out = (float*)d_out;

  unsigned short* Qb   = (unsigned short*)d_ws;        // 32*2048*64  (8 MB)
  unsigned short* Kb   = Qb + 32 * 2048 * 64;          // 8*2048*64   (2 MB)
  unsigned short* Vt   = Kb + 8 * 2048 * 64;           // 8*64*2048   (2 MB)
  unsigned short* ctxB = Vt + 8 * 64 * 2048;           // 2048*2048   (8 MB)

  qkv_rope_kernel<<<dim3(24, 16), 256, 0, stream>>>(x, Wq, Wk, Wv, cosT, sinT, Qb, Kb, Vt);
  attn_kernel<<<dim3(32, 16), 256, 0, stream>>>(Qb, Kb, Vt, ctxB);
  out_gemm_kernel<<<dim3(16, 16), 256, 0, stream>>>(ctxB, Wo, out);
}

// Round 2
// 212.994 us; speedup vs baseline: 1.6937x; 1.6937x over previous
//
#include <hip/hip_runtime.h>

typedef __bf16 bf16x8 __attribute__((ext_vector_type(8)));
typedef float f32x4 __attribute__((ext_vector_type(4)));

#define MFMA16 __builtin_amdgcn_mfma_f32_16x16x32_bf16

#define GLD16(gp, lp) __builtin_amdgcn_global_load_lds( \
    (const __attribute__((address_space(1))) void*)(gp), \
    (__attribute__((address_space(3))) void*)(lp), 16, 0, 0)

__device__ __forceinline__ unsigned short f2bf(float f) {
  union { float f; unsigned u; } v; v.f = f;
  unsigned r = v.u + 0x7fffu + ((v.u >> 16) & 1u);
  return (unsigned short)(r >> 16);
}

// ---------------------------------------------------------------------------
// Pre-pass 1: fp32 -> bf16 elementwise (for x).
// ---------------------------------------------------------------------------
__global__ __launch_bounds__(256)
void convert_bf16_kernel(const float* __restrict__ in, unsigned short* __restrict__ out) {
  int i = blockIdx.x * 256 + threadIdx.x;
  float4 a = *(const float4*)&in[i * 8];
  float4 b = *(const float4*)&in[i * 8 + 4];
  uint4 o;
  o.x = (unsigned)f2bf(a.x) | ((unsigned)f2bf(a.y) << 16);
  o.y = (unsigned)f2bf(a.z) | ((unsigned)f2bf(a.w) << 16);
  o.z = (unsigned)f2bf(b.x) | ((unsigned)f2bf(b.y) << 16);
  o.w = (unsigned)f2bf(b.z) | ((unsigned)f2bf(b.w) << 16);
  *(uint4*)&out[i * 8] = o;
}

// ---------------------------------------------------------------------------
// Pre-pass 2: W [K][N] fp32 -> W^T [N][K] bf16 (64x64 tiles via LDS).
// ---------------------------------------------------------------------------
__global__ __launch_bounds__(256)
void transpose_bf16_kernel(const float* __restrict__ in, unsigned short* __restrict__ out,
                           int K, int N) {
  __shared__ float tile[64][68];
  const int t = threadIdx.x;
  const int k0 = blockIdx.y * 64, n0 = blockIdx.x * 64;
#pragma unroll
  for (int i = 0; i < 4; ++i) {
    int r = i * 16 + (t >> 4);
    int cc = (t & 15) * 4;
    float4 v = *(const float4*)&in[(k0 + r) * N + n0 + cc];
    tile[r][cc] = v.x; tile[r][cc + 1] = v.y; tile[r][cc + 2] = v.z; tile[r][cc + 3] = v.w;
  }
  __syncthreads();
#pragma unroll
  for (int i = 0; i < 2; ++i) {
    int on = i * 32 + (t >> 3);
    int ok = (t & 7) * 8;
    uint4 o;
    o.x = (unsigned)f2bf(tile[ok + 0][on]) | ((unsigned)f2bf(tile[ok + 1][on]) << 16);
    o.y = (unsigned)f2bf(tile[ok + 2][on]) | ((unsigned)f2bf(tile[ok + 3][on]) << 16);
    o.z = (unsigned)f2bf(tile[ok + 4][on]) | ((unsigned)f2bf(tile[ok + 5][on]) << 16);
    o.w = (unsigned)f2bf(tile[ok + 6][on]) | ((unsigned)f2bf(tile[ok + 7][on]) << 16);
    *(uint4*)&out[(n0 + on) * K + k0 + ok] = o;
  }
}

// ---------------------------------------------------------------------------
// Kernel 1: QKV GEMM (m97 structure: bf16 A, bf16 B^T, global_load_lds(16),
// 128x128 tile, BK=64, 8 waves) with fused RoPE epilogue.
// Q -> [32][2048][64], K -> [8][2048][64], V -> transposed [8][64][2048].
// ---------------------------------------------------------------------------
__global__ __launch_bounds__(512)
void qkv_gemm_kernel(const unsigned short* __restrict__ xb,
                     const unsigned short* __restrict__ Wqt,
                     const unsigned short* __restrict__ Wkt,
                     const unsigned short* __restrict__ Wvt,
                     const float* __restrict__ cosT, const float* __restrict__ sinT,
                     unsigned short* __restrict__ Qb, unsigned short* __restrict__ Kb,
                     unsigned short* __restrict__ Vt)
{
  __shared__ unsigned short Al[128 * 64];
  __shared__ unsigned short Bl[128 * 64];
  const int t = threadIdx.x;
  const int w = t >> 6, l = t & 63, g = l >> 4, c = l & 15;
  const int wr = w >> 1, wc = w & 1;   // 4x2 waves: 32 rows x 64 cols each
  const int r0 = blockIdx.y * 128;
  const int c0 = blockIdx.x * 128;

  const unsigned short* B; int brow0;
  if (c0 < 2048)      { B = Wqt; brow0 = c0; }
  else if (c0 < 2560) { B = Wkt; brow0 = c0 - 2048; }
  else                { B = Wvt; brow0 = c0 - 2560; }

  f32x4 acc[2][4];
#pragma unroll
  for (int m = 0; m < 2; ++m)
#pragma unroll
    for (int n = 0; n < 4; ++n) acc[m][n] = (f32x4){0.f, 0.f, 0.f, 0.f};

  const int row = t >> 3, k8 = (t & 7) * 8;       // idx = t: rows 0..63
  const int row2 = row + 64;                       // idx = 512 + t: rows 64..127
  const unsigned lbase = (unsigned)(w << 6) * 8;   // wave-uniform LDS elem offset

  for (int kt = 0; kt < 2048; kt += 64) {
    GLD16(&xb[(r0 + row) * 2048 + kt + k8], &Al[lbase]);
    GLD16(&B[(brow0 + row) * 2048 + kt + k8], &Bl[lbase]);
    GLD16(&xb[(r0 + row2) * 2048 + kt + k8], &Al[4096 + lbase]);
    GLD16(&B[(brow0 + row2) * 2048 + kt + k8], &Bl[4096 + lbase]);
    __syncthreads();
#pragma unroll
    for (int ks = 0; ks < 2; ++ks) {
      bf16x8 aF[2], bF[4];
#pragma unroll
      for (int m = 0; m < 2; ++m)
        aF[m] = *(const bf16x8*)&Al[(wr * 32 + m * 16 + c) * 64 + ks * 32 + g * 8];
#pragma unroll
      for (int n = 0; n < 4; ++n)
        bF[n] = *(const bf16x8*)&Bl[(wc * 64 + n * 16 + c) * 64 + ks * 32 + g * 8];
#pragma unroll
      for (int m = 0; m < 2; ++m)
#pragma unroll
        for (int n = 0; n < 4; ++n)
          acc[m][n] = MFMA16(aF[m], bF[n], acc[m][n], 0, 0, 0);
    }
    __syncthreads();
  }

  const int wcol0 = c0 + wc * 64;  // wave's 64-col span == exactly one head
  if (c0 < 2560) {
    unsigned short* dst; int hh;
    if (c0 < 2048) { dst = Qb; hh = wcol0 >> 6; }
    else           { dst = Kb; hh = (wcol0 - 2048) >> 6; }
#pragma unroll
    for (int m = 0; m < 2; ++m) {
#pragma unroll
      for (int j = 0; j < 4; ++j) {
        int p = r0 + wr * 32 + m * 16 + g * 4 + j;
#pragma unroll
        for (int n = 0; n < 2; ++n) {  // RoPE: frag n (d<32) pairs with frag n+2
          int d = n * 16 + c;
          float cv = cosT[p * 64 + d];
          float sv = sinT[p * 64 + d];
          float lo = acc[m][n][j], hi = acc[m][n + 2][j];
          dst[(hh * 2048 + p) * 64 + d]      = f2bf(lo * cv - hi * sv);
          dst[(hh * 2048 + p) * 64 + d + 32] = f2bf(hi * cv + lo * sv);
        }
      }
    }
  } else {
    int kvh = (wcol0 - 2560) >> 6;
#pragma unroll
    for (int m = 0; m < 2; ++m) {
      int p0 = r0 + wr * 32 + m * 16 + g * 4;
#pragma unroll
      for (int n = 0; n < 4; ++n) {
        int d = n * 16 + c;
        ushort4 u;
        u.x = f2bf(acc[m][n][0]); u.y = f2bf(acc[m][n][1]);
        u.z = f2bf(acc[m][n][2]); u.w = f2bf(acc[m][n][3]);
        *(ushort4*)&Vt[(kvh * 64 + d) * 2048 + p0] = u;  // transposed store
      }
    }
  }
}

// ---------------------------------------------------------------------------
// Kernel 2: causal GQA flash attention (unchanged from round 1 — passed).
// ---------------------------------------------------------------------------
__global__ __launch_bounds__(256)
void attn_kernel(const unsigned short* __restrict__ Qb,
                 const unsigned short* __restrict__ Kb,
                 const unsigned short* __restrict__ Vt,
                 unsigned short* __restrict__ ctxO)
{
  __shared__ unsigned short Plds[4][32][72];
  const int t = threadIdx.x, w = t >> 6, l = t & 63, g = l >> 4, c = l & 15;
  const int h = blockIdx.x;
  const int qt = 15 - blockIdx.y;  // heavy (large-q) tiles first
  const int kvh = h >> 2;
  const int qb = qt * 128 + w * 32;

  bf16x8 qf[2][2];
#pragma unroll
  for (int m = 0; m < 2; ++m)
#pragma unroll
    for (int ks = 0; ks < 2; ++ks)
      qf[m][ks] = *(const bf16x8*)&Qb[(h * 2048 + qb + m * 16 + c) * 64 + ks * 32 + g * 8];

  f32x4 ctx[2][4];
  float mrow[2][4], lrow[2][4];
#pragma unroll
  for (int m = 0; m < 2; ++m) {
#pragma unroll
    for (int n = 0; n < 4; ++n) ctx[m][n] = (f32x4){0.f, 0.f, 0.f, 0.f};
#pragma unroll
    for (int j = 0; j < 4; ++j) { mrow[m][j] = -1e30f; lrow[m][j] = 0.f; }
  }

  const int ntile = (qb + 32 + 63) >> 6;
  for (int ti = 0; ti < ntile; ++ti) {
    const int kvb = ti * 64;
    f32x4 S[2][4];
#pragma unroll
    for (int m = 0; m < 2; ++m)
#pragma unroll
      for (int n = 0; n < 4; ++n) S[m][n] = (f32x4){0.f, 0.f, 0.f, 0.f};

#pragma unroll
    for (int ks = 0; ks < 2; ++ks) {
      bf16x8 kF[4];
#pragma unroll
      for (int nn = 0; nn < 4; ++nn)
        kF[nn] = *(const bf16x8*)&Kb[(kvh * 2048 + kvb + nn * 16 + c) * 64 + ks * 32 + g * 8];
#pragma unroll
      for (int m = 0; m < 2; ++m)
#pragma unroll
        for (int nn = 0; nn < 4; ++nn)
          S[m][nn] = MFMA16(qf[m][ks], kF[nn], S[m][nn], 0, 0, 0);
    }

    const bool diag = (kvb + 63 > qb);
#pragma unroll
    for (int m = 0; m < 2; ++m)
#pragma unroll
      for (int nn = 0; nn < 4; ++nn)
#pragma unroll
        for (int j = 0; j < 4; ++j) {
          float v = S[m][nn][j] * 0.125f;
          if (diag) {
            int qpos = qb + m * 16 + g * 4 + j;
            int kpos = kvb + nn * 16 + c;
            if (kpos > qpos) v = -1e30f;
          }
          S[m][nn][j] = v;
        }

    float fac[2][4];
#pragma unroll
    for (int m = 0; m < 2; ++m)
#pragma unroll
      for (int j = 0; j < 4; ++j) {
        float tm = fmaxf(fmaxf(S[m][0][j], S[m][1][j]), fmaxf(S[m][2][j], S[m][3][j]));
        tm = fmaxf(tm, __shfl_xor(tm, 1));
        tm = fmaxf(tm, __shfl_xor(tm, 2));
        tm = fmaxf(tm, __shfl_xor(tm, 4));
        tm = fmaxf(tm, __shfl_xor(tm, 8));
        float mn = fmaxf(mrow[m][j], tm);
        fac[m][j] = __expf(mrow[m][j] - mn);
        mrow[m][j] = mn;
      }

#pragma unroll
    for (int m = 0; m < 2; ++m)
#pragma unroll
      for (int j = 0; j < 4; ++j) {
        float rs = 0.f;
#pragma unroll
        for (int nn = 0; nn < 4; ++nn) {
          float p = __expf(S[m][nn][j] - mrow[m][j]);
          S[m][nn][j] = p;
          rs += p;
        }
        rs += __shfl_xor(rs, 1);
        rs += __shfl_xor(rs, 2);
        rs += __shfl_xor(rs, 4);
        rs += __shfl_xor(rs, 8);
        lrow[m][j] = lrow[m][j] * fac[m][j] + rs;
      }

#pragma unroll
    for (int m = 0; m < 2; ++m)
#pragma unroll
      for (int n = 0; n < 4; ++n)
#pragma unroll
        for (int j = 0; j < 4; ++j) ctx[m][n][j] *= fac[m][j];

#pragma unroll
    for (int m = 0; m < 2; ++m)
#pragma unroll
      for (int nn = 0; nn < 4; ++nn)
#pragma unroll
        for (int j = 0; j < 4; ++j)
          Plds[w][m * 16 + g * 4 + j][nn * 16 + c] = f2bf(S[m][nn][j]);

    bf16x8 pf[2][2];
#pragma unroll
    for (int m = 0; m < 2; ++m)
#pragma unroll
      for (int ks = 0; ks < 2; ++ks)
        pf[m][ks] = *(const bf16x8*)&Plds[w][m * 16 + c][ks * 32 + g * 8];

#pragma unroll
    for (int ks = 0; ks < 2; ++ks) {
      bf16x8 vF[4];
#pragma unroll
      for (int n = 0; n < 4; ++n)
        vF[n] = *(const bf16x8*)&Vt[(kvh * 64 + n * 16 + c) * 2048 + kvb + ks * 32 + g * 8];
#pragma unroll
      for (int m = 0; m < 2; ++m)
#pragma unroll
        for (int n = 0; n < 4; ++n)
          ctx[m][n] = MFMA16(pf[m][ks], vF[n], ctx[m][n], 0, 0, 0);
    }
  }

  float inv[2][4];
#pragma unroll
  for (int m = 0; m < 2; ++m)
#pragma unroll
    for (int j = 0; j < 4; ++j) inv[m][j] = 1.f / lrow[m][j];
#pragma unroll
  for (int m = 0; m < 2; ++m)
#pragma unroll
    for (int n = 0; n < 4; ++n)
#pragma unroll
      for (int j = 0; j < 4; ++j) {
        int p = qb + m * 16 + g * 4 + j;
        int d = n * 16 + c;
        ctxO[p * 2048 + h * 64 + d] = f2bf(ctx[m][n][j] * inv[m][j]);
      }
}

// ---------------------------------------------------------------------------
// Kernel 3: out = ctx(bf16) @ Wo^T-staged (m97 structure), fp32 output.
// ---------------------------------------------------------------------------
__global__ __launch_bounds__(512)
void out_gemm_kernel(const unsigned short* __restrict__ ctxB,
                     const unsigned short* __restrict__ Wot,
                     float* __restrict__ out)
{
  __shared__ unsigned short Al[128 * 64];
  __shared__ unsigned short Bl[128 * 64];
  const int t = threadIdx.x;
  const int w = t >> 6, l = t & 63, g = l >> 4, c = l & 15;
  const int wr = w >> 1, wc = w & 1;
  const int r0 = blockIdx.y * 128;
  const int c0 = blockIdx.x * 128;

  f32x4 acc[2][4];
#pragma unroll
  for (int m = 0; m < 2; ++m)
#pragma unroll
    for (int n = 0; n < 4; ++n) acc[m][n] = (f32x4){0.f, 0.f, 0.f, 0.f};

  const int row = t >> 3, k8 = (t & 7) * 8;
  const int row2 = row + 64;
  const unsigned lbase = (unsigned)(w << 6) * 8;

  for (int kt = 0; kt < 2048; kt += 64) {
    GLD16(&ctxB[(r0 + row) * 2048 + kt + k8], &Al[lbase]);
    GLD16(&Wot[(c0 + row) * 2048 + kt + k8], &Bl[lbase]);
    GLD16(&ctxB[(r0 + row2) * 2048 + kt + k8], &Al[4096 + lbase]);
    GLD16(&Wot[(c0 + row2) * 2048 + kt + k8], &Bl[4096 + lbase]);
    __syncthreads();
#pragma unroll
    for (int ks = 0; ks < 2; ++ks) {
      bf16x8 aF[2], bF[4];
#pragma unroll
      for (int m = 0; m < 2; ++m)
        aF[m] = *(const bf16x8*)&Al[(wr * 32 + m * 16 + c) * 64 + ks * 32 + g * 8];
#pragma unroll
      for (int n = 0; n < 4; ++n)
        bF[n] = *(const bf16x8*)&Bl[(wc * 64 + n * 16 + c) * 64 + ks * 32 + g * 8];
#pragma unroll
      for (int m = 0; m < 2; ++m)
#pragma unroll
        for (int n = 0; n < 4; ++n)
          acc[m][n] = MFMA16(aF[m], bF[n], acc[m][n], 0, 0, 0);
    }
    __syncthreads();
  }

#pragma unroll
  for (int m = 0; m < 2; ++m)
#pragma unroll
    for (int j = 0; j < 4; ++j) {
      int p = r0 + wr * 32 + m * 16 + g * 4 + j;
#pragma unroll
      for (int n = 0; n < 4; ++n)
        out[p * 2048 + c0 + wc * 64 + n * 16 + c] = acc[m][n][j];
    }
}

// ---------------------------------------------------------------------------
extern "C" void kernel_launch(void* const* d_in, const int* in_sizes, int n_in,
                              void* d_out, int out_size, void* d_ws, size_t ws_size,
                              hipStream_t stream) {
  const float* x    = (const float*)d_in[0];
  const float* Wq   = (const float*)d_in[1];
  const float* Wk   = (const float*)d_in[2];
  const float* Wv   = (const float*)d_in[3];
  const float* Wo   = (const float*)d_in[4];
  const float* cosT = (const float*)d_in[5];
  const float* sinT = (const float*)d_in[6];
  float* out = (float*)d_out;

  // Workspace layout (bf16 elems), with lifetime-based aliasing (32 MB total):
  //   buf0 (4M): xb   [read by qkv]  -> Wot  [written after qkv, read by outproj]
  //   buf1 (4M): Wqt  [read by qkv]  -> ctxB [written by attn, read by outproj]
  unsigned short* xb   = (unsigned short*)d_ws;            // 4M elems
  unsigned short* Wot  = xb;                                // alias (after qkv)
  unsigned short* Wqt  = xb + 4 * 1024 * 1024;              // 4M
  unsigned short* ctxB = Wqt;                               // alias (after qkv)
  unsigned short* Wkt  = Wqt + 4 * 1024 * 1024;             // 1M
  unsigned short* Wvt  = Wkt + 1024 * 1024;                 // 1M
  unsigned short* Qb   = Wvt + 1024 * 1024;                 // 4M
  unsigned short* Kb   = Qb + 4 * 1024 * 1024;              // 1M
  unsigned short* Vt   = Kb + 1024 * 1024;                  // 1M

  convert_bf16_kernel<<<2048, 256, 0, stream>>>(x, xb);
  transpose_bf16_kernel<<<dim3(32, 32), 256, 0, stream>>>(Wq, Wqt, 2048, 2048);
  transpose_bf16_kernel<<<dim3(8, 32), 256, 0, stream>>>(Wk, Wkt, 2048, 512);
  transpose_bf16_kernel<<<dim3(8, 32), 256, 0, stream>>>(Wv, Wvt, 2048, 512);

  qkv_gemm_kernel<<<dim3(24, 16), 512, 0, stream>>>(xb, Wqt, Wkt, Wvt, cosT, sinT, Qb, Kb, Vt);

  // Wo transpose placed AFTER qkv (Wot aliases xb, dead once qkv completes).
  transpose_bf16_kernel<<<dim3(32, 32), 256, 0, stream>>>(Wo, Wot, 2048, 2048);

  attn_kernel<<<dim3(32, 16), 256, 0, stream>>>(Qb, Kb, Vt, ctxB);
  out_gemm_kernel<<<dim3(16, 16), 512, 0, stream>>>(ctxB, Wot, out);
}